// Round 3
// baseline (313.700 us; speedup 1.0000x reference)
//
#include <hip/hip_runtime.h>

// SplineCNN on MI355X.
// Sparse edge extraction (adj ~6% dense, basis shared across layers);
// per-layer: split-bf16 MFMA GEMM [B*N,3K]x[3K,640] -> sparse aggregate
// (+root+bias+relu, emits next layer's split-bf16 input).
// Split-bf16: v = hi + lo (bf16 each); A slabs [hi|lo|hi], W slabs [hi;hi;lo]
// -> C = Ahi*Whi + Alo*Whi + Ahi*Wlo (drop lo*lo, ~5e-4 abs err).
// GEMM epilogue emits PAIR-PACKED fp16 taps: hwp[m][kx(3)][py(2)][f(64)] as
// fp16x2 dwords, py-pair = taps (kx,py),(kx,py+1); middle ky=1 duplicated.
// Aggregate (v3): HALF-WAVE KX-SPLIT — lanes 0-31 handle the kx0 slab,
// lanes 32-63 the kx0+1 slab of the SAME edge; each lane owns a feature
// pair. One dwordx2 gather per edge (coalesced 2x256B), v_dot2_f32_f16
// consumes the ky-pair in 1 instr/feature, edge index goes scalar via
// readfirstlane (wave-uniform), 4-deep static A/B/C/D pipeline keeps 16
// loads in flight. Halves combined once per row via shfl_xor(32).
// Layer-2 aggregate fuses global max-pool via uint-bitcast atomicMax (relu >= 0).

#define B_   32
#define N_   512
#define F_   64
#define CAP  128          // max neighbors per node (mean ~31, 128 is >>6 sigma)
#define NCOL 640          // 9*F (spline kernels) + F (root)

typedef short bf16x8 __attribute__((ext_vector_type(8)));
typedef float f32x4  __attribute__((ext_vector_type(4)));
typedef _Float16 f16x2v __attribute__((ext_vector_type(2)));

__device__ __forceinline__ unsigned short to_bf16_rne(float v) {
  unsigned u = __float_as_uint(v);
  unsigned r = u + 0x7fffu + ((u >> 16) & 1u);
  return (unsigned short)(r >> 16);
}
__device__ __forceinline__ float bf16_to_f(unsigned short h) {
  return __uint_as_float(((unsigned)h) << 16);
}

// ---------------- preprocess: edge lists + factored spline basis ----------------
// edge record: float4 { bitcast(idx0), fx, fy, 1.0 } where
// idx0 = m*384 + kx0*128 + ky0*64 (dword index into hwp, excl. feature f).
// w=1 marks valid; zero records give all-zero tap weights and idx0=0 (safe).
// Also zeroes the pooled-max buffer (blocks 0..2047, thread 0).
__global__ __launch_bounds__(512) void preprocess_kernel(
    const float* __restrict__ adj, const float* __restrict__ coord,
    float4* __restrict__ edge, int* __restrict__ cnt_out,
    float* __restrict__ deginv_out, unsigned int* __restrict__ gmax) {
  int row = blockIdx.x;          // b*N + n
  int b = row >> 9;
  int tid = threadIdx.x;         // == m
  int lane = tid & 63, wave = tid >> 6;
  if (row < B_ * F_ && tid == 0) gmax[row] = 0u;
  __shared__ int wcnt[8];
  float a = adj[(size_t)row * N_ + tid];
  bool flag = (a != 0.0f);
  unsigned long long ball = __ballot(flag);
  if (lane == 0) wcnt[wave] = __popcll(ball);
  __syncthreads();
  int woff = 0, total = 0;
  #pragma unroll
  for (int i = 0; i < 8; ++i) { int c = wcnt[i]; if (i < wave) woff += c; total += c; }
  if (flag) {
    int pos = woff + __popcll(ball & ((1ULL << lane) - 1));
    if (pos < CAP) {
      int m = tid;
      float cxn = coord[(size_t)row * 2 + 0];
      float cyn = coord[(size_t)row * 2 + 1];
      float cxm = coord[(size_t)(b * N_ + m) * 2 + 0];
      float cym = coord[(size_t)(b * N_ + m) * 2 + 1];
      float vx = (cxm - cxn + 1.0f) * 0.5f * 2.0f;
      float vy = (cym - cyn + 1.0f) * 0.5f * 2.0f;
      float i0x = fminf(fmaxf(floorf(vx), 0.0f), 1.0f);
      float i0y = fminf(fmaxf(floorf(vy), 0.0f), 1.0f);
      float fx = vx - i0x, fy = vy - i0y;
      int idx0 = m * 384 + (int)i0x * 128 + (int)i0y * 64;
      edge[(size_t)row * CAP + pos] =
          make_float4(__int_as_float(idx0), fx, fy, 1.0f);
    }
  }
  if (tid == 0) {
    cnt_out[row] = total > CAP ? CAP : total;
    deginv_out[row] = 1.0f / (float)(total > 0 ? total : 1);
  }
}

// ---------------- convert x (fp32 [M,128]) -> split-bf16 A [M, 384] ----------------
__global__ void convx_kernel(const float* __restrict__ x, unsigned short* __restrict__ a) {
  int idx = blockIdx.x * blockDim.x + threadIdx.x;
  if (idx >= B_ * N_ * 128) return;
  int row = idx >> 7, k = idx & 127;
  float v = x[idx];
  unsigned short hi = to_bf16_rne(v);
  unsigned short lo = to_bf16_rne(v - bf16_to_f(hi));
  size_t base = (size_t)row * 384;
  a[base + k] = hi;
  a[base + 128 + k] = lo;
  a[base + 256 + k] = hi;
}

// ---- pack all 3 layers' w (9 slices)+root -> W^T split-bf16 (slabs hi,hi,lo) ----
__global__ void packw_all_kernel(
    const float* __restrict__ w0, const float* __restrict__ root0,
    const float* __restrict__ w1, const float* __restrict__ root1,
    const float* __restrict__ w2, const float* __restrict__ root2,
    unsigned short* __restrict__ wt0, unsigned short* __restrict__ wt1,
    unsigned short* __restrict__ wt2) {
  int idx = blockIdx.x * blockDim.x + threadIdx.x;
  const int T0 = NCOL * 128, T1 = NCOL * 64;
  const float* w; const float* root; unsigned short* wt; int cin; int r;
  if (idx < T0)           { w = w0; root = root0; wt = wt0; cin = 128; r = idx; }
  else if (idx < T0 + T1) { w = w1; root = root1; wt = wt1; cin = 64;  r = idx - T0; }
  else if (idx < T0 + 2 * T1) { w = w2; root = root2; wt = wt2; cin = 64; r = idx - T0 - T1; }
  else return;
  int n = r / cin, k = r - n * cin;
  int kk = n >> 6, f = n & 63;
  float v = (kk < 9) ? w[((size_t)kk * cin + k) * F_ + f]
                     : root[(size_t)k * F_ + f];
  unsigned short hi = to_bf16_rne(v);
  unsigned short lo = to_bf16_rne(v - bf16_to_f(hi));
  size_t base = (size_t)n * (3 * cin);
  wt[base + k] = hi;
  wt[base + cin + k] = hi;
  wt[base + 2 * cin + k] = lo;
}

// ---------------- split-bf16 MFMA GEMM: [M,640] = A[M,KP] * Wt[640,KP]^T ----------------
// 128x128 tile, 256 threads = 4 waves (2x2 of 64x64), 16x16x32 bf16 MFMA, BK=64.
// LDS rows padded +8 bf16 (stride 144B = 9 words -> conflict-free b128 frag reads).
// Epilogue: each 64-col slab is wave-uniform (k = (bn+nw)>>6). Tap slabs k<9 ->
// pair-packed fp16 hwp (ky<=1 -> py=ky slot lo; ky>=1 -> py=ky-1 slot hi);
// root slab k==9 -> fp32 rootf.
#define BK 64
#define LDK (BK + 8)
__global__ __launch_bounds__(256) void gemm_mfma_kernel(
    const unsigned short* __restrict__ A,   // [M][KP]
    const unsigned short* __restrict__ Wt,  // [640][KP]  (W^T, n-major)
    _Float16* __restrict__ hwp,             // [M][3 kx][2 py][64 f][2] fp16
    float* __restrict__ rootf,              // [M][64] fp32 root slab
    int KP) {
  __shared__ unsigned short As[128 * LDK];
  __shared__ unsigned short Ws[128 * LDK];
  int bm = blockIdx.x * 128;
  int bn = blockIdx.y * 128;
  int tid = threadIdx.x;
  int wave = tid >> 6, lane = tid & 63;
  int mw = (wave & 1) * 64, nw = (wave >> 1) * 64;
  int lr = lane & 15, quad = lane >> 4;

  f32x4 acc[4][4] = {};
  for (int k0 = 0; k0 < KP; k0 += BK) {
    #pragma unroll
    for (int i = 0; i < 4; ++i) {
      int c = tid + i * 256;            // 0..1023 chunks of 16B
      int row = c >> 3, ck = (c & 7) * 8;
      *(float4*)&As[row * LDK + ck] =
          *(const float4*)&A[(size_t)(bm + row) * KP + k0 + ck];
      *(float4*)&Ws[row * LDK + ck] =
          *(const float4*)&Wt[(size_t)(bn + row) * KP + k0 + ck];
    }
    __syncthreads();
    #pragma unroll
    for (int kk = 0; kk < BK; kk += 32) {
      bf16x8 af[4], bf[4];
      #pragma unroll
      for (int i = 0; i < 4; ++i)
        af[i] = *(const bf16x8*)&As[(mw + 16 * i + lr) * LDK + kk + quad * 8];
      #pragma unroll
      for (int j = 0; j < 4; ++j)
        bf[j] = *(const bf16x8*)&Ws[(nw + 16 * j + lr) * LDK + kk + quad * 8];
      #pragma unroll
      for (int i = 0; i < 4; ++i)
        #pragma unroll
        for (int j = 0; j < 4; ++j)
          acc[i][j] = __builtin_amdgcn_mfma_f32_16x16x32_bf16(af[i], bf[j], acc[i][j], 0, 0, 0);
    }
    __syncthreads();
  }
  // epilogue: C/D layout col=lane&15, row=quad*4+reg (m89-verified).
  // n = bn + nw + 16j + lr spans exactly one 64-col slab per wave.
  int kslab = (bn + nw) >> 6;   // 0..9, wave-uniform
  if (kslab < 9) {
    int kx = kslab / 3;
    int ky = kslab - 3 * kx;
    #pragma unroll
    for (int i = 0; i < 4; ++i)
      #pragma unroll
      for (int j = 0; j < 4; ++j)
        #pragma unroll
        for (int r = 0; r < 4; ++r) {
          int m = bm + mw + 16 * i + quad * 4 + r;
          int fcol = 16 * j + lr;
          _Float16 h = (_Float16)acc[i][j][r];
          // ushort index = 2*(m*384 + kx*128 + py*64 + f) + hslot
          size_t base = ((size_t)m * 384 + kx * 128 + fcol) * 2;
          if (ky <= 1) hwp[base + (size_t)ky * 128] = h;
          if (ky >= 1) hwp[base + (size_t)(ky - 1) * 128 + 1] = h;
        }
  } else {
    #pragma unroll
    for (int i = 0; i < 4; ++i)
      #pragma unroll
      for (int j = 0; j < 4; ++j)
        #pragma unroll
        for (int r = 0; r < 4; ++r) {
          int m = bm + mw + 16 * i + quad * 4 + r;
          rootf[(size_t)m * F_ + 16 * j + lr] = acc[i][j][r];
        }
  }
}

// ---------------- sparse aggregate (half-wave kx-split) ----------------
// 256 threads = 4 waves, one row per wave. XCD-swizzled (blockIdx&7 = XCD).
// Lane l: half = l>>5 selects kx slab (kx0 / kx0+1); fp = l&31 selects the
// feature pair (2fp, 2fp+1). Per edge ONE dwordx2 gather (8B/lane, coalesced
// 2x256B) -> two f16x2 ky-pairs; v_dot2_f32_f16 with packed fp16 weights
// (wx*by0, wx*by1) accumulates each feature. Edge index is wave-uniform ->
// readfirstlane + scalar base. 4-deep static pipeline (16 loads in flight).
// Halves summed via shfl_xor(32); lanes<32 write hi+lo slabs, lanes>=32 the
// duplicate hi slab of next layer's split-bf16 A.
__global__ __launch_bounds__(256) void aggregate_kernel(
    const unsigned int* __restrict__ hwp,   // dword view of pair-packed taps
    const float* __restrict__ rootf,
    const float4* __restrict__ edge,
    const int* __restrict__ cnt, const float* __restrict__ deginv,
    const float* __restrict__ bias,
    unsigned short* __restrict__ aout,
    unsigned int* __restrict__ gmax) {
  __shared__ float4 esh[4][CAP + 32];
  int wave = threadIdx.x >> 6;
  int lane = threadIdx.x & 63;
  int half = lane >> 5;          // 0: kx0 slab, 1: kx0+1 slab
  int fp = lane & 31;            // feature pair index
  int xcd = blockIdx.x & 7;
  int j = blockIdx.x >> 3;
  int b = xcd * 4 + (j >> 7);
  int row = b * N_ + ((j & 127) << 2) + wave;
  int c = cnt[row];
  int cpad = (c + 15) & ~15;
  size_t ebase = (size_t)row * CAP;
  for (int i = lane; i < cpad + 28; i += 64)
    esh[wave][i] = (i < c) ? edge[ebase + i] : make_float4(0.f, 0.f, 0.f, 0.f);
  __syncthreads();

  float di = deginv[row];
  // lane-constant dword offset into the row's 384-dword record
  const unsigned int* hb = hwp + (size_t)b * N_ * 384 + half * 128 + fp * 2;
  float acc0 = 0.f, acc1 = 0.f;

#define LOADG(P, e) { \
    int s0 = __builtin_amdgcn_readfirstlane(__float_as_int(esh[wave][(e) + 0].x)); \
    int s1 = __builtin_amdgcn_readfirstlane(__float_as_int(esh[wave][(e) + 1].x)); \
    int s2 = __builtin_amdgcn_readfirstlane(__float_as_int(esh[wave][(e) + 2].x)); \
    int s3 = __builtin_amdgcn_readfirstlane(__float_as_int(esh[wave][(e) + 3].x)); \
    P##0 = *(const uint2*)(hb + s0); \
    P##1 = *(const uint2*)(hb + s1); \
    P##2 = *(const uint2*)(hb + s2); \
    P##3 = *(const uint2*)(hb + s3); }

#define CONS1(U, er) { \
    float bx1 = (er).y, by1 = (er).z, vv = (er).w; \
    float wx = half ? bx1 : (vv - bx1); \
    f16x2v wpk; \
    wpk[0] = (_Float16)(wx * (vv - by1)); \
    wpk[1] = (_Float16)(wx * by1); \
    unsigned wp = __builtin_bit_cast(unsigned, wpk); \
    asm("v_dot2_f32_f16 %0, %1, %2, %0" : "+v"(acc0) : "v"((U).x), "v"(wp)); \
    asm("v_dot2_f32_f16 %0, %1, %2, %0" : "+v"(acc1) : "v"((U).y), "v"(wp)); }

#define CONSG(P, e) { \
    float4 e0r = esh[wave][(e) + 0]; CONS1(P##0, e0r); \
    float4 e1r = esh[wave][(e) + 1]; CONS1(P##1, e1r); \
    float4 e2r = esh[wave][(e) + 2]; CONS1(P##2, e2r); \
    float4 e3r = esh[wave][(e) + 3]; CONS1(P##3, e3r); }

  uint2 A0, A1, A2, A3, B0, B1, B2, B3, C0, C1, C2, C3, D0, D1, D2, D3;
  if (cpad > 0) {
    LOADG(A, 0); LOADG(B, 4); LOADG(C, 8);
    for (int e0 = 0; e0 < cpad; e0 += 16) {
      LOADG(D, e0 + 12);
      CONSG(A, e0);
      LOADG(A, e0 + 16);      // overshoot reads zero-pad records (safe)
      CONSG(B, e0 + 4);
      LOADG(B, e0 + 20);
      CONSG(C, e0 + 8);
      LOADG(C, e0 + 24);
      CONSG(D, e0 + 12);
    }
  }
#undef LOADG
#undef CONS1
#undef CONSG

  // combine kx halves: both halves end up with the full sum (xor is symmetric)
  float t0 = acc0 + __shfl_xor(acc0, 32);
  float t1 = acc1 + __shfl_xor(acc1, 32);
  int f0 = fp * 2;
  float2 rt = *(const float2*)&rootf[(size_t)row * F_ + f0];
  float2 bi = *(const float2*)&bias[f0];
  float v0 = fmaxf(t0 * di + rt.x + bi.x, 0.0f);
  float v1 = fmaxf(t1 * di + rt.y + bi.y, 0.0f);
  if (aout) {
    unsigned short h0 = to_bf16_rne(v0), h1 = to_bf16_rne(v1);
    unsigned hh = (unsigned)h0 | ((unsigned)h1 << 16);
    size_t base = (size_t)row * 192;
    if (half == 0) {
      *(unsigned*)&aout[base + f0] = hh;
      unsigned short l0 = to_bf16_rne(v0 - bf16_to_f(h0));
      unsigned short l1 = to_bf16_rne(v1 - bf16_to_f(h1));
      *(unsigned*)&aout[base + 64 + f0] = (unsigned)l0 | ((unsigned)l1 << 16);
    } else {
      *(unsigned*)&aout[base + 128 + f0] = hh;
    }
  }
  if (gmax && half == 0) {
    // relu output >= 0 -> IEEE bits monotone under unsigned compare
    atomicMax(&gmax[b * F_ + f0], __float_as_uint(v0));
    atomicMax(&gmax[b * F_ + f0 + 1], __float_as_uint(v1));
  }
}

// ---------------- FC from pooled features ----------------
__global__ __launch_bounds__(64) void fc_kernel(
    const float* __restrict__ g, const float* __restrict__ fcw,
    const float* __restrict__ fcb, float* __restrict__ out) {
  int b = blockIdx.x;
  int f = threadIdx.x;
  __shared__ float gs[64];
  gs[f] = g[b * F_ + f];
  __syncthreads();
  if (f < 10) {
    float s = fcb[f];
    #pragma unroll
    for (int c = 0; c < 64; ++c) s += gs[c] * fcw[c * 10 + f];
    out[b * 10 + f] = s;
  }
}

extern "C" void kernel_launch(void* const* d_in, const int* in_sizes, int n_in,
                              void* d_out, int out_size, void* d_ws, size_t ws_size,
                              hipStream_t stream) {
  const float* x     = (const float*)d_in[0];
  const float* coord = (const float*)d_in[1];
  const float* adj   = (const float*)d_in[2];
  const float* w0    = (const float*)d_in[3];
  const float* root0 = (const float*)d_in[4];
  const float* b0    = (const float*)d_in[5];
  const float* w1    = (const float*)d_in[6];
  const float* root1 = (const float*)d_in[7];
  const float* b1    = (const float*)d_in[8];
  const float* w2    = (const float*)d_in[9];
  const float* root2 = (const float*)d_in[10];
  const float* b2    = (const float*)d_in[11];
  const float* fcw   = (const float*)d_in[12];
  const float* fcb   = (const float*)d_in[13];
  float* out = (float*)d_out;

  char* ws = (char*)d_ws;
  size_t off = 0;
  auto alloc = [&](size_t bytes) {
    void* p = ws + off;
    off = (off + bytes + 255) & ~(size_t)255;
    return p;
  };
  const int R = B_ * N_;  // 16384
  float4* edge    = (float4*)alloc((size_t)R * CAP * 16);
  int*    cnt     = (int*)   alloc((size_t)R * 4);
  float*  deginv  = (float*) alloc((size_t)R * 4);
  unsigned short* abf0 = (unsigned short*)alloc((size_t)R * 384 * 2);
  unsigned short* abfN = (unsigned short*)alloc((size_t)R * 192 * 2);
  unsigned short* wt0  = (unsigned short*)alloc((size_t)NCOL * 384 * 2);
  unsigned short* wt1  = (unsigned short*)alloc((size_t)NCOL * 192 * 2);
  unsigned short* wt2  = (unsigned short*)alloc((size_t)NCOL * 192 * 2);
  _Float16* hwp   = (_Float16*)alloc((size_t)R * 384 * 4);  // pair-packed taps
  float*  rootf   = (float*) alloc((size_t)R * F_ * 4);
  unsigned int* gmax = (unsigned int*)alloc((size_t)B_ * F_ * 4);

  preprocess_kernel<<<R, 512, 0, stream>>>(adj, coord, edge, cnt, deginv, gmax);
  convx_kernel<<<(R * 128 + 255) / 256, 256, 0, stream>>>(x, abf0);
  packw_all_kernel<<<(NCOL * (128 + 64 + 64) + 255) / 256, 256, 0, stream>>>(
      w0, root0, w1, root1, w2, root2, wt0, wt1, wt2);

  // layer 0 (Cin=128, KP=384)
  gemm_mfma_kernel<<<dim3(R / 128, NCOL / 128), 256, 0, stream>>>(abf0, wt0, hwp, rootf, 384);
  aggregate_kernel<<<R / 4, 256, 0, stream>>>((const unsigned int*)hwp, rootf, edge, cnt, deginv, b0, abfN, nullptr);

  // layer 1 (Cin=64, KP=192)
  gemm_mfma_kernel<<<dim3(R / 128, NCOL / 128), 256, 0, stream>>>(abfN, wt1, hwp, rootf, 192);
  aggregate_kernel<<<R / 4, 256, 0, stream>>>((const unsigned int*)hwp, rootf, edge, cnt, deginv, b1, abfN, nullptr);

  // layer 2 (Cin=64, KP=192) — fused max-pool
  gemm_mfma_kernel<<<dim3(R / 128, NCOL / 128), 256, 0, stream>>>(abfN, wt2, hwp, rootf, 192);
  aggregate_kernel<<<R / 4, 256, 0, stream>>>((const unsigned int*)hwp, rootf, edge, cnt, deginv, b2, nullptr, gmax);

  fc_kernel<<<B_, 64, 0, stream>>>((const float*)gmax, fcw, fcb, out);
}

// Round 4
// 277.829 us; speedup vs baseline: 1.1291x; 1.1291x over previous
//
#include <hip/hip_runtime.h>

// SplineCNN on MI355X.
// Sparse edge extraction (adj ~6% dense, basis shared across layers);
// per-layer: split-bf16 MFMA GEMM [B*N,3K]x[3K,640] -> sparse aggregate
// (+root+bias+relu, emits next layer's split-bf16 input).
// Split-bf16: v = hi + lo (bf16 each); A slabs [hi|lo|hi], W slabs [hi;hi;lo]
// -> C = Ahi*Whi + Alo*Whi + Ahi*Wlo (drop lo*lo, ~5e-4 abs err).
// GEMM epilogue emits PAIR-PACKED fp16 taps: hwp[m][kx(3)][py(2)][f(64)] as
// fp16x2 dwords, py-pair = taps (kx,py),(kx,py+1); middle ky=1 duplicated.
// An edge's 4 taps = 2 dword loads (base, base+512B).
// XCD-ALIGNED PIPELINE (this round): every kernel maps batch b's rows to
// XCD b>>2 (blockIdx%8 == XCD round-robin heuristic), so the GEMM's hwp/rootf
// writes sit dirty in the SAME XCD L2 the aggregate gathers from (~3.1MB hot
// slice < 4MiB), and the aggregate's aout writes feed the next GEMM's A reads
// locally. Previously these gathers were cross-XCD -> L3/HBM latency (~700cy),
// which made aggregate time invariant to bytes/instructions (R0-R2 evidence).
// Layer-2 aggregate fuses global max-pool via uint-bitcast atomicMax (relu >= 0).

#define B_   32
#define N_   512
#define F_   64
#define CAP  128          // max neighbors per node (mean ~31, 128 is >>6 sigma)
#define NCOL 640          // 9*F (spline kernels) + F (root)

typedef short bf16x8 __attribute__((ext_vector_type(8)));
typedef float f32x4  __attribute__((ext_vector_type(4)));
typedef _Float16 f16x2 __attribute__((ext_vector_type(2)));

__device__ __forceinline__ unsigned short to_bf16_rne(float v) {
  unsigned u = __float_as_uint(v);
  unsigned r = u + 0x7fffu + ((u >> 16) & 1u);
  return (unsigned short)(r >> 16);
}
__device__ __forceinline__ float bf16_to_f(unsigned short h) {
  return __uint_as_float(((unsigned)h) << 16);
}

// ---------------- preprocess: edge lists + factored spline basis ----------------
// edge record: float4 { bitcast(idx0), fx, fy, 1.0 } where
// idx0 = m*384 + kx0*128 + ky0*64 (dword index into hwp, excl. feature f).
// w=1 marks valid; zero records give all-zero tap weights and idx0=0 (safe).
// XCD-aligned: block i -> row (i&7)*2048 + (i>>3)  (batch b on XCD b>>2).
// Blocks 0..2047 also zero the pooled-max buffer.
__global__ __launch_bounds__(512) void preprocess_kernel(
    const float* __restrict__ adj, const float* __restrict__ coord,
    float4* __restrict__ edge, int* __restrict__ cnt_out,
    float* __restrict__ deginv_out, unsigned int* __restrict__ gmax) {
  int row = (blockIdx.x & 7) * 2048 + (blockIdx.x >> 3);
  int b = row >> 9;
  int tid = threadIdx.x;         // == m
  int lane = tid & 63, wave = tid >> 6;
  if (blockIdx.x < B_ * F_ && tid == 0) gmax[blockIdx.x] = 0u;
  __shared__ int wcnt[8];
  float a = adj[(size_t)row * N_ + tid];
  bool flag = (a != 0.0f);
  unsigned long long ball = __ballot(flag);
  if (lane == 0) wcnt[wave] = __popcll(ball);
  __syncthreads();
  int woff = 0, total = 0;
  #pragma unroll
  for (int i = 0; i < 8; ++i) { int c = wcnt[i]; if (i < wave) woff += c; total += c; }
  if (flag) {
    int pos = woff + __popcll(ball & ((1ULL << lane) - 1));
    if (pos < CAP) {
      int m = tid;
      float cxn = coord[(size_t)row * 2 + 0];
      float cyn = coord[(size_t)row * 2 + 1];
      float cxm = coord[(size_t)(b * N_ + m) * 2 + 0];
      float cym = coord[(size_t)(b * N_ + m) * 2 + 1];
      float vx = (cxm - cxn + 1.0f) * 0.5f * 2.0f;
      float vy = (cym - cyn + 1.0f) * 0.5f * 2.0f;
      float i0x = fminf(fmaxf(floorf(vx), 0.0f), 1.0f);
      float i0y = fminf(fmaxf(floorf(vy), 0.0f), 1.0f);
      float fx = vx - i0x, fy = vy - i0y;
      int idx0 = m * 384 + (int)i0x * 128 + (int)i0y * 64;
      edge[(size_t)row * CAP + pos] =
          make_float4(__int_as_float(idx0), fx, fy, 1.0f);
    }
  }
  if (tid == 0) {
    cnt_out[row] = total > CAP ? CAP : total;
    deginv_out[row] = 1.0f / (float)(total > 0 ? total : 1);
  }
}

// ---------------- convert x (fp32 [M,128]) -> split-bf16 A [M, 384] ----------------
__global__ void convx_kernel(const float* __restrict__ x, unsigned short* __restrict__ a) {
  int idx = blockIdx.x * blockDim.x + threadIdx.x;
  if (idx >= B_ * N_ * 128) return;
  int row = idx >> 7, k = idx & 127;
  float v = x[idx];
  unsigned short hi = to_bf16_rne(v);
  unsigned short lo = to_bf16_rne(v - bf16_to_f(hi));
  size_t base = (size_t)row * 384;
  a[base + k] = hi;
  a[base + 128 + k] = lo;
  a[base + 256 + k] = hi;
}

// ---- pack all 3 layers' w (9 slices)+root -> W^T split-bf16 (slabs hi,hi,lo) ----
__global__ void packw_all_kernel(
    const float* __restrict__ w0, const float* __restrict__ root0,
    const float* __restrict__ w1, const float* __restrict__ root1,
    const float* __restrict__ w2, const float* __restrict__ root2,
    unsigned short* __restrict__ wt0, unsigned short* __restrict__ wt1,
    unsigned short* __restrict__ wt2) {
  int idx = blockIdx.x * blockDim.x + threadIdx.x;
  const int T0 = NCOL * 128, T1 = NCOL * 64;
  const float* w; const float* root; unsigned short* wt; int cin; int r;
  if (idx < T0)           { w = w0; root = root0; wt = wt0; cin = 128; r = idx; }
  else if (idx < T0 + T1) { w = w1; root = root1; wt = wt1; cin = 64;  r = idx - T0; }
  else if (idx < T0 + 2 * T1) { w = w2; root = root2; wt = wt2; cin = 64; r = idx - T0 - T1; }
  else return;
  int n = r / cin, k = r - n * cin;
  int kk = n >> 6, f = n & 63;
  float v = (kk < 9) ? w[((size_t)kk * cin + k) * F_ + f]
                     : root[(size_t)k * F_ + f];
  unsigned short hi = to_bf16_rne(v);
  unsigned short lo = to_bf16_rne(v - bf16_to_f(hi));
  size_t base = (size_t)n * (3 * cin);
  wt[base + k] = hi;
  wt[base + cin + k] = hi;
  wt[base + 2 * cin + k] = lo;
}

// ---------------- split-bf16 MFMA GEMM: [M,640] = A[M,KP] * Wt[640,KP]^T ----------------
// 128x128 tile, 256 threads = 4 waves (2x2 of 64x64), 16x16x32 bf16 MFMA, BK=64.
// LDS rows padded +8 bf16 (stride 144B = 9 words -> conflict-free b128 frag reads).
// 1D grid 640 = 8 XCDs x (16 m-tiles x 5 n-tiles): block i -> xcd = i&7,
// mx = 16*xcd + (i>>3)/5, ny = (i>>3)%5 -> batch (mx>>2) lands on XCD batch>>2,
// matching the aggregate's mapping (hwp/rootf writes stay in the local L2).
// Epilogue: each 64-col slab is wave-uniform (k = (bn+nw)>>6). Tap slabs k<9 ->
// pair-packed fp16 hwp (ky<=1 -> py=ky slot lo; ky>=1 -> py=ky-1 slot hi);
// root slab k==9 -> fp32 rootf.
#define BK 64
#define LDK (BK + 8)
__global__ __launch_bounds__(256) void gemm_mfma_kernel(
    const unsigned short* __restrict__ A,   // [M][KP]
    const unsigned short* __restrict__ Wt,  // [640][KP]  (W^T, n-major)
    _Float16* __restrict__ hwp,             // [M][3 kx][2 py][64 f][2] fp16
    float* __restrict__ rootf,              // [M][64] fp32 root slab
    int KP) {
  __shared__ unsigned short As[128 * LDK];
  __shared__ unsigned short Ws[128 * LDK];
  int xcd = blockIdx.x & 7, g = blockIdx.x >> 3;   // g in 0..79
  int gq = g / 5;
  int bm = ((xcd << 4) + gq) * 128;
  int bn = (g - 5 * gq) * 128;
  int tid = threadIdx.x;
  int wave = tid >> 6, lane = tid & 63;
  int mw = (wave & 1) * 64, nw = (wave >> 1) * 64;
  int lr = lane & 15, quad = lane >> 4;

  f32x4 acc[4][4] = {};
  for (int k0 = 0; k0 < KP; k0 += BK) {
    #pragma unroll
    for (int i = 0; i < 4; ++i) {
      int c = tid + i * 256;            // 0..1023 chunks of 16B
      int row = c >> 3, ck = (c & 7) * 8;
      *(float4*)&As[row * LDK + ck] =
          *(const float4*)&A[(size_t)(bm + row) * KP + k0 + ck];
      *(float4*)&Ws[row * LDK + ck] =
          *(const float4*)&Wt[(size_t)(bn + row) * KP + k0 + ck];
    }
    __syncthreads();
    #pragma unroll
    for (int kk = 0; kk < BK; kk += 32) {
      bf16x8 af[4], bf[4];
      #pragma unroll
      for (int i = 0; i < 4; ++i)
        af[i] = *(const bf16x8*)&As[(mw + 16 * i + lr) * LDK + kk + quad * 8];
      #pragma unroll
      for (int j = 0; j < 4; ++j)
        bf[j] = *(const bf16x8*)&Ws[(nw + 16 * j + lr) * LDK + kk + quad * 8];
      #pragma unroll
      for (int i = 0; i < 4; ++i)
        #pragma unroll
        for (int j = 0; j < 4; ++j)
          acc[i][j] = __builtin_amdgcn_mfma_f32_16x16x32_bf16(af[i], bf[j], acc[i][j], 0, 0, 0);
    }
    __syncthreads();
  }
  // epilogue: C/D layout col=lane&15, row=quad*4+reg (m89-verified).
  // n = bn + nw + 16j + lr spans exactly one 64-col slab per wave.
  int kslab = (bn + nw) >> 6;   // 0..9, wave-uniform
  if (kslab < 9) {
    int kx = kslab / 3;
    int ky = kslab - 3 * kx;
    #pragma unroll
    for (int i = 0; i < 4; ++i)
      #pragma unroll
      for (int j = 0; j < 4; ++j)
        #pragma unroll
        for (int r = 0; r < 4; ++r) {
          int m = bm + mw + 16 * i + quad * 4 + r;
          int fcol = 16 * j + lr;
          _Float16 h = (_Float16)acc[i][j][r];
          // ushort index = 2*(m*384 + kx*128 + py*64 + f) + hslot
          size_t base = ((size_t)m * 384 + kx * 128 + fcol) * 2;
          if (ky <= 1) hwp[base + (size_t)ky * 128] = h;
          if (ky >= 1) hwp[base + (size_t)(ky - 1) * 128 + 1] = h;
        }
  } else {
    #pragma unroll
    for (int i = 0; i < 4; ++i)
      #pragma unroll
      for (int j = 0; j < 4; ++j)
        #pragma unroll
        for (int r = 0; r < 4; ++r) {
          int m = bm + mw + 16 * i + quad * 4 + r;
          rootf[(size_t)m * F_ + 16 * j + lr] = acc[i][j][r];
        }
  }
}

// ---------------- sparse aggregate ----------------
// 256 threads = 4 waves, one row per wave. XCD-swizzled (blockIdx&7 = XCD,
// matching the GEMM's write mapping -> gathers hit the local L2).
// Edge lists staged to LDS, padded to x8 (+8 zero records for overshoot).
// Per edge: 2 dword gathers from pair-packed fp16 hwp (base, base+512B);
// manual 2-deep A/B register pipeline keeps next group's 8 loads in flight
// while converting+FMA-ing the current group.
// Emits next layer's split-bf16 A (aout: [row][192] = hi|lo|hi) and/or gmax.
__global__ __launch_bounds__(256) void aggregate_kernel(
    const unsigned int* __restrict__ hwp,   // dword view of pair-packed taps
    const float* __restrict__ rootf,
    const float4* __restrict__ edge,
    const int* __restrict__ cnt, const float* __restrict__ deginv,
    const float* __restrict__ bias,
    unsigned short* __restrict__ aout,
    unsigned int* __restrict__ gmax) {
  __shared__ float4 esh[4][CAP + 8];
  int wave = threadIdx.x >> 6;
  int lane = threadIdx.x & 63;
  int f = lane;
  int xcd = blockIdx.x & 7;
  int j = blockIdx.x >> 3;
  int b = xcd * 4 + (j >> 7);
  int row = b * N_ + ((j & 127) << 2) + wave;
  int c = cnt[row];
  int cpad = (c + 7) & ~7;
  size_t ebase = (size_t)row * CAP;
  for (int i = lane; i < cpad + 8; i += 64)
    esh[wave][i] = (i < c) ? edge[ebase + i] : make_float4(0.f, 0.f, 0.f, 0.f);
  __syncthreads();

  float di = deginv[row];
  const unsigned int* hb = hwp + (size_t)b * N_ * 384;
  float acc0 = 0.f, acc1 = 0.f, acc2 = 0.f, acc3 = 0.f;

#define LOADG(P, e) { \
    int i0 = __float_as_int(esh[wave][(e) + 0].x) + f; \
    int i1 = __float_as_int(esh[wave][(e) + 1].x) + f; \
    int i2 = __float_as_int(esh[wave][(e) + 2].x) + f; \
    int i3 = __float_as_int(esh[wave][(e) + 3].x) + f; \
    P##0 = hb[i0]; P##1 = hb[i0 + 128]; \
    P##2 = hb[i1]; P##3 = hb[i1 + 128]; \
    P##4 = hb[i2]; P##5 = hb[i2 + 128]; \
    P##6 = hb[i3]; P##7 = hb[i3 + 128]; }

#define CONS1(ulo, uhi, er, acc) { \
    float bx1 = (er).y, by1 = (er).z, vv = (er).w; \
    float bx0 = vv - bx1, by0 = vv - by1; \
    f16x2 p0 = __builtin_bit_cast(f16x2, ulo); \
    f16x2 p1 = __builtin_bit_cast(f16x2, uhi); \
    acc += (bx0 * by0) * (float)p0[0] + (bx0 * by1) * (float)p0[1] \
         + (bx1 * by0) * (float)p1[0] + (bx1 * by1) * (float)p1[1]; }

#define CONSG(P, e) { \
    float4 e0r = esh[wave][(e) + 0]; CONS1(P##0, P##1, e0r, acc0); \
    float4 e1r = esh[wave][(e) + 1]; CONS1(P##2, P##3, e1r, acc1); \
    float4 e2r = esh[wave][(e) + 2]; CONS1(P##4, P##5, e2r, acc2); \
    float4 e3r = esh[wave][(e) + 3]; CONS1(P##6, P##7, e3r, acc3); }

  unsigned A0 = 0, A1 = 0, A2 = 0, A3 = 0, A4 = 0, A5 = 0, A6 = 0, A7 = 0;
  unsigned B0, B1, B2, B3, B4, B5, B6, B7;
  if (cpad > 0) {
    LOADG(A, 0);
    for (int e0 = 0; e0 < cpad; e0 += 8) {
      LOADG(B, e0 + 4);          // in flight behind A's consume
      CONSG(A, e0);
      LOADG(A, e0 + 8);          // overshoot reads zero-pad records (safe)
      CONSG(B, e0 + 4);
    }
  }
#undef LOADG
#undef CONS1
#undef CONSG

  float rootv = rootf[(size_t)row * F_ + f];
  float val = fmaxf(((acc0 + acc1) + (acc2 + acc3)) * di + rootv + bias[f], 0.0f);
  if (aout) {
    unsigned short hi = to_bf16_rne(val);
    unsigned short lo = to_bf16_rne(val - bf16_to_f(hi));
    size_t base = (size_t)row * 192;
    aout[base + f] = hi;
    aout[base + 64 + f] = lo;
    aout[base + 128 + f] = hi;
  }
  if (gmax) {
    // relu output >= 0 -> IEEE bits monotone under unsigned compare
    atomicMax(&gmax[b * F_ + f], __float_as_uint(val));
  }
}

// ---------------- FC from pooled features ----------------
__global__ __launch_bounds__(64) void fc_kernel(
    const float* __restrict__ g, const float* __restrict__ fcw,
    const float* __restrict__ fcb, float* __restrict__ out) {
  int b = blockIdx.x;
  int f = threadIdx.x;
  __shared__ float gs[64];
  gs[f] = g[b * F_ + f];
  __syncthreads();
  if (f < 10) {
    float s = fcb[f];
    #pragma unroll
    for (int c = 0; c < 64; ++c) s += gs[c] * fcw[c * 10 + f];
    out[b * 10 + f] = s;
  }
}

extern "C" void kernel_launch(void* const* d_in, const int* in_sizes, int n_in,
                              void* d_out, int out_size, void* d_ws, size_t ws_size,
                              hipStream_t stream) {
  const float* x     = (const float*)d_in[0];
  const float* coord = (const float*)d_in[1];
  const float* adj   = (const float*)d_in[2];
  const float* w0    = (const float*)d_in[3];
  const float* root0 = (const float*)d_in[4];
  const float* b0    = (const float*)d_in[5];
  const float* w1    = (const float*)d_in[6];
  const float* root1 = (const float*)d_in[7];
  const float* b1    = (const float*)d_in[8];
  const float* w2    = (const float*)d_in[9];
  const float* root2 = (const float*)d_in[10];
  const float* b2    = (const float*)d_in[11];
  const float* fcw   = (const float*)d_in[12];
  const float* fcb   = (const float*)d_in[13];
  float* out = (float*)d_out;

  char* ws = (char*)d_ws;
  size_t off = 0;
  auto alloc = [&](size_t bytes) {
    void* p = ws + off;
    off = (off + bytes + 255) & ~(size_t)255;
    return p;
  };
  const int R = B_ * N_;  // 16384
  float4* edge    = (float4*)alloc((size_t)R * CAP * 16);
  int*    cnt     = (int*)   alloc((size_t)R * 4);
  float*  deginv  = (float*) alloc((size_t)R * 4);
  unsigned short* abf0 = (unsigned short*)alloc((size_t)R * 384 * 2);
  unsigned short* abfN = (unsigned short*)alloc((size_t)R * 192 * 2);
  unsigned short* wt0  = (unsigned short*)alloc((size_t)NCOL * 384 * 2);
  unsigned short* wt1  = (unsigned short*)alloc((size_t)NCOL * 192 * 2);
  unsigned short* wt2  = (unsigned short*)alloc((size_t)NCOL * 192 * 2);
  _Float16* hwp   = (_Float16*)alloc((size_t)R * 384 * 4);  // pair-packed taps
  float*  rootf   = (float*) alloc((size_t)R * F_ * 4);
  unsigned int* gmax = (unsigned int*)alloc((size_t)B_ * F_ * 4);

  preprocess_kernel<<<R, 512, 0, stream>>>(adj, coord, edge, cnt, deginv, gmax);
  convx_kernel<<<(R * 128 + 255) / 256, 256, 0, stream>>>(x, abf0);
  packw_all_kernel<<<(NCOL * (128 + 64 + 64) + 255) / 256, 256, 0, stream>>>(
      w0, root0, w1, root1, w2, root2, wt0, wt1, wt2);

  // layer 0 (Cin=128, KP=384)
  gemm_mfma_kernel<<<640, 256, 0, stream>>>(abf0, wt0, hwp, rootf, 384);
  aggregate_kernel<<<R / 4, 256, 0, stream>>>((const unsigned int*)hwp, rootf, edge, cnt, deginv, b0, abfN, nullptr);

  // layer 1 (Cin=64, KP=192)
  gemm_mfma_kernel<<<640, 256, 0, stream>>>(abfN, wt1, hwp, rootf, 192);
  aggregate_kernel<<<R / 4, 256, 0, stream>>>((const unsigned int*)hwp, rootf, edge, cnt, deginv, b1, abfN, nullptr);

  // layer 2 (Cin=64, KP=192) — fused max-pool
  gemm_mfma_kernel<<<640, 256, 0, stream>>>(abfN, wt2, hwp, rootf, 192);
  aggregate_kernel<<<R / 4, 256, 0, stream>>>((const unsigned int*)hwp, rootf, edge, cnt, deginv, b2, nullptr, gmax);

  fc_kernel<<<B_, 64, 0, stream>>>((const float*)gmax, fcw, fcb, out);
}